// Round 8
// baseline (192.848 us; speedup 1.0000x reference)
//
#include <hip/hip_runtime.h>
#include <math.h>

#define SEQ 4096
#define DM 512
#define NH 8
#define DH 64
#define TQK (3 * DM)   // 1536
#define QSCALE 0.18033688011112042f   // log2(e)/8 : folds softmax scale + base-2 exp

typedef __attribute__((ext_vector_type(8))) short bf16x8;
typedef __attribute__((ext_vector_type(4))) short short4v;
typedef __attribute__((ext_vector_type(4))) float floatx4;
typedef unsigned short ushort_t;

__device__ __forceinline__ floatx4 mfma16(bf16x8 a, bf16x8 b, floatx4 c) {
    return __builtin_amdgcn_mfma_f32_16x16x32_bf16(a, b, c, 0, 0, 0);
}
// legacy K=16 bf16 MFMA: A/B = 4 bf16 (2 VGPRs) — A-layout == C-layout of the K=32 op
__device__ __forceinline__ floatx4 mfma16k16(short4v a, short4v b, floatx4 c) {
    return __builtin_amdgcn_mfma_f32_16x16x16bf16_1k(a, b, c, 0, 0, 0);
}
__device__ __forceinline__ float ex2(float x) { return __builtin_amdgcn_exp2f(x); }

__device__ __forceinline__ unsigned int pk2(float a, float b) {
    unsigned int ua = __float_as_uint(a); ua = (ua + 0x7FFFu + ((ua >> 16) & 1u)) >> 16;
    unsigned int ub = __float_as_uint(b); ub = (ub + 0x7FFFu + ((ub >> 16) & 1u)) >> 16;
    return ua | (ub << 16);
}
__device__ __forceinline__ unsigned short f2bf(float x) {
    unsigned int u = __float_as_uint(x);
    return (unsigned short)((u + 0x7FFFu + ((u >> 16) & 1u)) >> 16);
}
// truncating pack: low16 = hi16(a), high16 = hi16(b) — 1 v_perm
__device__ __forceinline__ unsigned int pkt(float a, float b) {
    return __builtin_amdgcn_perm(__float_as_uint(b), __float_as_uint(a), 0x07060302u);
}
__device__ __forceinline__ float bflo(unsigned int u) { return __uint_as_float(u << 16); }
__device__ __forceinline__ float bfhi(unsigned int u) { return __uint_as_float(u & 0xFFFF0000u); }
__device__ __forceinline__ short4v mk4(unsigned int lo, unsigned int hi) {
    union { unsigned int u[2]; short4v v; } x; x.u[0] = lo; x.u[1] = hi; return x.v;
}

__device__ __forceinline__ void gload_lds16(const void* g, void* l) {
    __builtin_amdgcn_global_load_lds(
        (const __attribute__((address_space(1))) unsigned int*)g,
        (__attribute__((address_space(3))) unsigned int*)l, 16, 0, 0);
}

// ---------------- fused prep: x->bf16, W_in^T (Q cols pre-scaled), W_out^T ----------------
__global__ __launch_bounds__(256) void prep(const float* __restrict__ x,
                                            const float* __restrict__ W_in,
                                            const float* __restrict__ W_out,
                                            ushort_t* __restrict__ xb,
                                            ushort_t* __restrict__ wti,
                                            ushort_t* __restrict__ wto) {
    __shared__ float T[64][65];
    const int bid = blockIdx.x, tid = threadIdx.x;
    if (bid < 1024) {
        const int i = bid * 256 + tid;
        const float4* p = (const float4*)x + (size_t)i * 2;
        float4 f0 = p[0], f1 = p[1];
        ((uint4*)xb)[i] = make_uint4(pk2(f0.x, f0.y), pk2(f0.z, f0.w),
                                     pk2(f1.x, f1.y), pk2(f1.z, f1.w));
        return;
    }
    const float* W; ushort_t* WT; int N, K, n0, k0; bool qscale;
    if (bid < 1216) { int id = bid - 1024; W = W_in;  WT = wti; N = TQK; K = DM;
                      n0 = (id % 24) * 64; k0 = (id / 24) * 64; qscale = true; }
    else            { int id = bid - 1216; W = W_out; WT = wto; N = DM;  K = DM;
                      n0 = (id % 8) * 64;  k0 = (id / 8) * 64;  qscale = false; }
    {
        const int r = tid >> 2, g = tid & 3;
        const float* src = W + (size_t)(k0 + r) * N + n0 + g * 16;
#pragma unroll
        for (int i = 0; i < 4; i++) {
            float4 f = ((const float4*)src)[i];
            T[g * 16 + i * 4 + 0][r] = f.x;
            T[g * 16 + i * 4 + 1][r] = f.y;
            T[g * 16 + i * 4 + 2][r] = f.z;
            T[g * 16 + i * 4 + 3][r] = f.w;
        }
    }
    __syncthreads();
    const int nr = tid >> 2, g2 = tid & 3;
    const float sc = (qscale && (n0 + nr < DM)) ? QSCALE : 1.0f;
    unsigned int pk[8];
#pragma unroll
    for (int j = 0; j < 8; j++)
        pk[j] = pk2(T[nr][g2 * 16 + 2 * j] * sc, T[nr][g2 * 16 + 2 * j + 1] * sc);
    ushort_t* dst = WT + (size_t)(n0 + nr) * K + k0 + g2 * 16;
    ((uint4*)dst)[0] = make_uint4(pk[0], pk[1], pk[2], pk[3]);
    ((uint4*)dst)[1] = make_uint4(pk[4], pk[5], pk[6], pk[7]);
}

// ---------------- GEMM1: qkv = x @ W_in^T + b_in (bf16 out, V diverted transposed) -------
__global__ __launch_bounds__(256) void gemm_in(const ushort_t* __restrict__ A,
                                               const ushort_t* __restrict__ BT,
                                               const float* __restrict__ bias,
                                               ushort_t* __restrict__ Cv,
                                               ushort_t* __restrict__ vt_out) {
    __shared__ __align__(16) ushort_t As[2][128 * 64];
    __shared__ __align__(16) ushort_t Bs[2][128 * 64];
    const int tid  = threadIdx.x;
    const int lane = tid & 63;
    const int w    = tid >> 6;
    const int quad = lane >> 4;
    const int ln   = lane & 15;
    const int row0 = blockIdx.y * 128;
    const int col0 = blockIdx.x * 128;
    const int wm = w >> 1, wn = w & 1;
    const int srow = lane >> 3;
    const int js   = (lane & 7) ^ srow;
    const int K = DM, N = TQK;

    floatx4 acc[4][4];
#pragma unroll
    for (int i = 0; i < 4; i++)
#pragma unroll
        for (int j = 0; j < 4; j++) acc[i][j] = (floatx4){0.f, 0.f, 0.f, 0.f};

#pragma unroll
    for (int i = 0; i < 4; i++) {
        const int c = w * 4 + i;
        gload_lds16(A  + (size_t)(row0 + c * 8 + srow) * K + js * 8, &As[0][c * 512]);
        gload_lds16(BT + (size_t)(col0 + c * 8 + srow) * K + js * 8, &Bs[0][c * 512]);
    }

    for (int kt = 0; kt < 8; kt++) {
        const int cur = kt & 1;
        __syncthreads();
        if (kt < 7) {
            const int k0n = (kt + 1) << 6;
#pragma unroll
            for (int i = 0; i < 4; i++) {
                const int c = w * 4 + i;
                gload_lds16(A  + (size_t)(row0 + c * 8 + srow) * K + k0n + js * 8, &As[cur ^ 1][c * 512]);
                gload_lds16(BT + (size_t)(col0 + c * 8 + srow) * K + k0n + js * 8, &Bs[cur ^ 1][c * 512]);
            }
        }
#pragma unroll
        for (int s = 0; s < 2; s++) {
            bf16x8 af[4], bfr[4];
#pragma unroll
            for (int i = 0; i < 4; i++) {
                const int lm = wm * 64 + i * 16 + ln;
                af[i] = *(const bf16x8*)&As[cur][lm * 64 + ((s * 4 + quad) ^ (ln & 7)) * 8];
                const int lnn = wn * 64 + i * 16 + ln;
                bfr[i] = *(const bf16x8*)&Bs[cur][lnn * 64 + ((s * 4 + quad) ^ (ln & 7)) * 8];
            }
#pragma unroll
            for (int i = 0; i < 4; i++)
#pragma unroll
                for (int j = 0; j < 4; j++)
                    acc[i][j] = mfma16(af[i], bfr[j], acc[i][j]);
        }
    }

    if (col0 >= 2 * DM) {   // V region -> transposed bf16 [d][seq]
#pragma unroll
        for (int j = 0; j < 4; j++) {
            const int n = col0 + wn * 64 + j * 16 + ln;
            const float bv = bias[n];
#pragma unroll
            for (int i = 0; i < 4; i++) {
                const int mb = row0 + wm * 64 + i * 16 + quad * 4;
                uint2 pkd;
                pkd.x = pk2(acc[i][j][0] + bv, acc[i][j][1] + bv);
                pkd.y = pk2(acc[i][j][2] + bv, acc[i][j][3] + bv);
                *(uint2*)&vt_out[(size_t)(n - 2 * DM) * SEQ + mb] = pkd;
            }
        }
        return;
    }

#pragma unroll
    for (int j = 0; j < 4; j++) {
        const int n = col0 + wn * 64 + j * 16 + ln;
        const float bv = bias[n] * ((n < DM) ? QSCALE : 1.0f);
#pragma unroll
        for (int i = 0; i < 4; i++) {
            const int mb = row0 + wm * 64 + i * 16 + quad * 4;
#pragma unroll
            for (int r = 0; r < 4; r++)
                Cv[(size_t)(mb + r) * N + n] = f2bf(acc[i][j][r] + bv);
        }
    }
}

// ---------------- split-K flash attention, transposed-S: 256 thr, 4 waves, 32 q/wave -----
// Grid (144, 8). blockIdx.x enumerates (qt, chunk) with qt DESCENDING (long
// chunks dispatch first). q-tile = 128 rows; K-tiles of 64 keys; chunk <= 8.
// S^T = K.Q^T puts q on lane&15: per-lane softmax; P stays in registers and
// feeds mfma_16x16x16 (A-layout == C-layout) — zero LDS traffic for P.
__global__ __launch_bounds__(256, 3) void attn_split(const ushort_t* __restrict__ qkv_b,
                                                     const ushort_t* __restrict__ vt,
                                                     ushort_t* __restrict__ po,
                                                     float2* __restrict__ pml) {
    __shared__ __align__(16) ushort_t Ks[2][64 * 64];
    __shared__ __align__(16) ushort_t Vs[2][64 * 64];

    const int tid  = threadIdx.x;
    const int lane = tid & 63;
    const int w    = tid >> 6;          // 0..3
    const int quad = lane >> 4;
    const int ln   = lane & 15;
    const int h    = blockIdx.y;
    const int lnx7 = ln & 7;
    const int qh   = quad >> 1, ql = quad & 1;

    // slot -> (qt, chunk c), qt descending
    int qt = 0, nc = 1, cc = 0;
    {
        int bx = blockIdx.x, acc = 0;
        for (int q = 31; q >= 0; --q) {
            const int n = (q >> 2) + 1;
            if (bx < acc + n) { qt = q; nc = n; cc = bx - acc; break; }
            acc += n;
        }
    }
    const int T   = 2 * qt + 2;
    const int jt0 = (cc * T) / nc;
    const int jt1 = ((cc + 1) * T) / nc;
    const int q0  = qt * 128;

    // Q B-frags from global (bf16, pre-scaled by log2e/8): 2 q-groups x 2 k-halves
    bf16x8 qb[2][2];
#pragma unroll
    for (int qg = 0; qg < 2; qg++) {
        const ushort_t* qr = qkv_b + (size_t)(q0 + w * 32 + qg * 16 + ln) * TQK + h * DH;
        qb[qg][0] = *(const bf16x8*)(qr + quad * 8);
        qb[qg][1] = *(const bf16x8*)(qr + quad * 8 + 32);
    }

    float m_[2] = {-INFINITY, -INFINITY}, l_[2] = {0.f, 0.f};
    floatx4 o[2][4];
#pragma unroll
    for (int qg = 0; qg < 2; qg++)
#pragma unroll
        for (int dt = 0; dt < 4; dt++) o[qg][dt] = (floatx4){0.f, 0.f, 0.f, 0.f};

    const int srow = lane >> 3;
    const int js   = (lane & 7) ^ srow;

    {   // prologue: stage jt0 into buffer 0
        const int k0 = jt0 * 64;
#pragma unroll
        for (int i = 0; i < 2; i++) {
            const int cg = w * 2 + i;
            gload_lds16(qkv_b + (size_t)(k0 + cg * 8 + srow) * TQK + DM + h * DH + js * 8,
                        &Ks[0][cg * 512]);
            gload_lds16(vt + (size_t)(h * DH + cg * 8 + srow) * SEQ + k0 + js * 8,
                        &Vs[0][cg * 512]);
        }
    }

    for (int jt = jt0; jt < jt1; ++jt) {
        const int cur = (jt - jt0) & 1;
        const int k0  = jt * 64;
        __syncthreads();
        if (jt + 1 < jt1) {
            const int k0n = (jt + 1) * 64;
#pragma unroll
            for (int i = 0; i < 2; i++) {
                const int cg = w * 2 + i;
                gload_lds16(qkv_b + (size_t)(k0n + cg * 8 + srow) * TQK + DM + h * DH + js * 8,
                            &Ks[cur ^ 1][cg * 512]);
                gload_lds16(vt + (size_t)(h * DH + cg * 8 + srow) * SEQ + k0n + js * 8,
                            &Vs[cur ^ 1][cg * 512]);
            }
        }

        // K A-frags (shared by both q-groups)
        bf16x8 kf[4][2];
#pragma unroll
        for (int t = 0; t < 4; t++) {
            kf[t][0] = *(const bf16x8*)&Ks[cur][(t * 16 + ln) * 64 + ((quad) ^ lnx7) * 8];
            kf[t][1] = *(const bf16x8*)&Ks[cur][(t * 16 + ln) * 64 + ((4 + quad) ^ lnx7) * 8];
        }
        // V B-frags for the K=16 PV mfma (shared by both q-groups): 4 consecutive keys
        short4v vf[4][4];
#pragma unroll
        for (int t = 0; t < 4; t++)
#pragma unroll
            for (int dt = 0; dt < 4; dt++)
                vf[t][dt] = *(const short4v*)&Vs[cur][(dt * 16 + ln) * 64 +
                                                     (((2 * t + qh) ^ lnx7) << 3) + (ql << 2)];

#pragma unroll
        for (int qg = 0; qg < 2; qg++) {
            const int q = q0 + w * 32 + qg * 16 + ln;   // this lane's q-row

            // ---- S^T tile: rows=keys, cols=q (lane&15) ----
            floatx4 sa[4];
#pragma unroll
            for (int t = 0; t < 4; t++) {
                floatx4 a = (floatx4){0.f, 0.f, 0.f, 0.f};
                a = mfma16(kf[t][0], qb[qg][0], a);
                a = mfma16(kf[t][1], qb[qg][1], a);
                sa[t] = a;
            }

            if (k0 + 63 > q0 + w * 32 + qg * 16) {   // tile may violate causality
#pragma unroll
                for (int t = 0; t < 4; t++)
#pragma unroll
                    for (int r = 0; r < 4; r++) {
                        const int key = k0 + t * 16 + quad * 4 + r;
                        if (key > q) sa[t][r] = -INFINITY;
                    }
            }

            // ---- per-lane (per-q) online softmax ----
            float mx = sa[0][0];
#pragma unroll
            for (int t = 0; t < 4; t++)
#pragma unroll
                for (int r = 0; r < 4; r++) mx = fmaxf(mx, sa[t][r]);
            mx = fmaxf(mx, __shfl_xor(mx, 16));
            mx = fmaxf(mx, __shfl_xor(mx, 32));
            const float mn = fmaxf(fmaxf(m_[qg], mx), -1e30f);
            const float alpha = ex2(m_[qg] - mn);
            m_[qg] = mn;

            float p[4][4];
            float ls = 0.f;
#pragma unroll
            for (int t = 0; t < 4; t++)
#pragma unroll
                for (int r = 0; r < 4; r++) {
                    p[t][r] = ex2(sa[t][r] - mn);
                    ls += p[t][r];
                }
            ls += __shfl_xor(ls, 16);
            ls += __shfl_xor(ls, 32);
            l_[qg] = l_[qg] * alpha + ls;

            // broadcast alpha of output rows (q index quad*4+r) within 16-group
            float a4[4];
#pragma unroll
            for (int r = 0; r < 4; r++)
                a4[r] = __shfl(alpha, (lane & 48) | (quad * 4 + r));
#pragma unroll
            for (int dt = 0; dt < 4; dt++)
#pragma unroll
                for (int r = 0; r < 4; r++) o[qg][dt][r] *= a4[r];

            // pack P as K=16 A-frags (in-register, truncating bf16)
            short4v pf[4];
#pragma unroll
            for (int t = 0; t < 4; t++)
                pf[t] = mk4(pkt(p[t][0], p[t][1]), pkt(p[t][2], p[t][3]));

            // ---- O[q][d] += P V ----
#pragma unroll
            for (int dt = 0; dt < 4; dt++)
#pragma unroll
                for (int t = 0; t < 4; t++)
                    o[qg][dt] = mfma16k16(pf[t], vf[t][dt], o[qg][dt]);
        }
    }

    // partials: unnormalized bf16 O (po[slot][q128][d64]) + fp32 (m,l)
    const size_t pbase  = ((size_t)h * 144 + blockIdx.x) * (128 * 64);
    const size_t mlbase = ((size_t)h * 144 + blockIdx.x) * 128;
#pragma unroll
    for (int qg = 0; qg < 2; qg++) {
#pragma unroll
        for (int dt = 0; dt < 4; dt++)
#pragma unroll
            for (int r = 0; r < 4; r++)
                po[pbase + (size_t)(w * 32 + qg * 16 + quad * 4 + r) * 64 + dt * 16 + ln] =
                    (ushort_t)(__float_as_uint(o[qg][dt][r]) >> 16);
        if (quad == 0)
            pml[mlbase + w * 32 + qg * 16 + ln] = make_float2(m_[qg], l_[qg]);
    }
}

// ---------------- combine partials -> attn_out bf16 [SEQ][DM] ----------------
// Grid (32, 8) x 512 thr: q = tid>>2 (128 rows), dg = tid&3 (16-d slice).
__global__ __launch_bounds__(512) void attn_combine(const ushort_t* __restrict__ po,
                                                    const float2* __restrict__ pml,
                                                    ushort_t* __restrict__ aob) {
    const int qt = blockIdx.x, h = blockIdx.y;
    const int nc = (qt >> 2) + 1;
    int sbase = 0;
    for (int q = 31; q > qt; --q) sbase += (q >> 2) + 1;
    const int row = threadIdx.x >> 2, g = threadIdx.x & 3;

    float2 ml[8];
    float M = -INFINITY;
    for (int ci = 0; ci < nc; ci++) {
        ml[ci] = pml[((size_t)h * 144 + sbase + ci) * 128 + row];
        M = fmaxf(M, ml[ci].x);
    }
    float L = 0.f;
    float acc[16];
#pragma unroll
    for (int j = 0; j < 16; j++) acc[j] = 0.f;

    for (int ci = 0; ci < nc; ci++) {
        const float wgt = ex2(ml[ci].x - M);
        L += wgt * ml[ci].y;
        const ushort_t* p = po + ((size_t)h * 144 + sbase + ci) * (128 * 64)
                               + (size_t)row * 64 + g * 16;
        uint4 u0 = ((const uint4*)p)[0];
        uint4 u1 = ((const uint4*)p)[1];
        const unsigned int uu[8] = {u0.x, u0.y, u0.z, u0.w, u1.x, u1.y, u1.z, u1.w};
#pragma unroll
        for (int j = 0; j < 8; j++) {
            acc[2 * j]     += wgt * bflo(uu[j]);
            acc[2 * j + 1] += wgt * bfhi(uu[j]);
        }
    }
    const float inv = 1.0f / L;
    unsigned int pk[8];
#pragma unroll
    for (int j = 0; j < 8; j++)
        pk[j] = pk2(acc[2 * j] * inv, acc[2 * j + 1] * inv);
    ushort_t* dst = aob + (size_t)(qt * 128 + row) * DM + h * DH + g * 16;
    ((uint4*)dst)[0] = make_uint4(pk[0], pk[1], pk[2], pk[3]);
    ((uint4*)dst)[1] = make_uint4(pk[4], pk[5], pk[6], pk[7]);
}

// ---------------- GEMM2: out = aob @ W_out^T + b_out (fp32), 128x64 tiles ----------------
__global__ __launch_bounds__(256) void gemm_out(const ushort_t* __restrict__ A,
                                                const ushort_t* __restrict__ BT,
                                                const float* __restrict__ bias,
                                                float* __restrict__ out) {
    __shared__ __align__(16) ushort_t As[2][128 * 64];
    __shared__ __align__(16) ushort_t Bs[2][64 * 64];
    const int tid  = threadIdx.x;
    const int lane = tid & 63;
    const int w    = tid >> 6;
    const int quad = lane >> 4;
    const int ln   = lane & 15;
    const int row0 = blockIdx.y * 128;
    const int col0 = blockIdx.x * 64;
    const int wm = w >> 1, wn = w & 1;
    const int srow = lane >> 3;
    const int js   = (lane & 7) ^ srow;

    floatx4 acc[4][2];
#pragma unroll
    for (int i = 0; i < 4; i++)
#pragma unroll
        for (int j = 0; j < 2; j++) acc[i][j] = (floatx4){0.f, 0.f, 0.f, 0.f};

#pragma unroll
    for (int i = 0; i < 4; i++) {
        const int c = w * 4 + i;
        gload_lds16(A + (size_t)(row0 + c * 8 + srow) * DM + js * 8, &As[0][c * 512]);
    }
#pragma unroll
    for (int i = 0; i < 2; i++) {
        const int c = w * 2 + i;
        gload_lds16(BT + (size_t)(col0 + c * 8 + srow) * DM + js * 8, &Bs[0][c * 512]);
    }

    for (int kt = 0; kt < 8; kt++) {
        const int cur = kt & 1;
        __syncthreads();
        if (kt < 7) {
            const int k0n = (kt + 1) << 6;
#pragma unroll
            for (int i = 0; i < 4; i++) {
                const int c = w * 4 + i;
                gload_lds16(A + (size_t)(row0 + c * 8 + srow) * DM + k0n + js * 8, &As[cur ^ 1][c * 512]);
            }
#pragma unroll
            for (int i = 0; i < 2; i++) {
                const int c = w * 2 + i;
                gload_lds16(BT + (size_t)(col0 + c * 8 + srow) * DM + k0n + js * 8, &Bs[cur ^ 1][c * 512]);
            }
        }
#pragma unroll
        for (int s = 0; s < 2; s++) {
            bf16x8 af[4], bfr[2];
#pragma unroll
            for (int i = 0; i < 4; i++) {
                const int lm = wm * 64 + i * 16 + ln;
                af[i] = *(const bf16x8*)&As[cur][lm * 64 + ((s * 4 + quad) ^ (ln & 7)) * 8];
            }
#pragma unroll
            for (int j = 0; j < 2; j++) {
                const int lnn = wn * 32 + j * 16 + ln;
                bfr[j] = *(const bf16x8*)&Bs[cur][lnn * 64 + ((s * 4 + quad) ^ (ln & 7)) * 8];
            }
#pragma unroll
            for (int i = 0; i < 4; i++)
#pragma unroll
                for (int j = 0; j < 2; j++)
                    acc[i][j] = mfma16(af[i], bfr[j], acc[i][j]);
        }
    }

#pragma unroll
    for (int j = 0; j < 2; j++) {
        const int n = col0 + wn * 32 + j * 16 + ln;
        const float bv = bias[n];
#pragma unroll
        for (int i = 0; i < 4; i++) {
            const int mb = row0 + wm * 64 + i * 16 + quad * 4;
#pragma unroll
            for (int r = 0; r < 4; r++)
                out[(size_t)(mb + r) * DM + n] = acc[i][j][r] + bv;
        }
    }
}

extern "C" void kernel_launch(void* const* d_in, const int* in_sizes, int n_in,
                              void* d_out, int out_size, void* d_ws, size_t ws_size,
                              hipStream_t stream) {
    const float* x     = (const float*)d_in[0];
    const float* W_in  = (const float*)d_in[1];
    const float* b_in  = (const float*)d_in[2];
    const float* W_out = (const float*)d_in[3];
    const float* b_out = (const float*)d_in[4];
    float* out = (float*)d_out;

    char* ws = (char*)d_ws;
    ushort_t* xb    = (ushort_t*)ws;                    //  4 MB   x bf16 [4096][512]
    ushort_t* wti   = (ushort_t*)(ws + (4u  << 20));    //  1.5 MB W_in^T bf16 (Q cols x QSCALE)
    ushort_t* wto   = (ushort_t*)(ws + (6u  << 20));    //  0.5 MB W_out^T bf16
    ushort_t* qkv_b = (ushort_t*)(ws + (7u  << 20));    // 12 MB   qkv bf16 (V third unused)
    ushort_t* vtb   = (ushort_t*)(ws + (19u << 20));    //  4 MB   V^T bf16 [512][4096]
    ushort_t* po    = (ushort_t*)(ws + (23u << 20));    // 18.9 MB partial O bf16 [8][144][128*64]
    float2*   pml   = (float2*)  (ws + (42u << 20));    //  1.2 MB partial (m,l) [8][144][128]
    ushort_t* aob   = (ushort_t*)(ws + (44u << 20));    //  4 MB   attn out bf16 [4096][512]

    // 0) fused prep: x->bf16 | W_in^T | W_out^T
    prep<<<1280, 256, 0, stream>>>(x, W_in, W_out, xb, wti, wto);

    // 1) qkv = x @ W_in + b_in; Q pre-scaled; V diverted transposed to vtb
    gemm_in<<<dim3(TQK / 128, SEQ / 128), 256, 0, stream>>>(xb, wti, b_in, qkv_b, vtb);

    // 2) split-K causal flash attention (transposed-S, register-resident P)
    attn_split<<<dim3(144, NH), 256, 0, stream>>>(qkv_b, vtb, po, pml);

    // 3) merge partials -> aob
    attn_combine<<<dim3(SEQ / 128, NH), 512, 0, stream>>>(po, pml, aob);

    // 4) out = aob @ W_out + b_out (fp32)
    gemm_out<<<dim3(DM / 64, SEQ / 128), 256, 0, stream>>>(aob, wto, b_out, out);
}

// Round 9
// 156.048 us; speedup vs baseline: 1.2358x; 1.2358x over previous
//
#include <hip/hip_runtime.h>
#include <math.h>

#define SEQ 4096
#define DM 512
#define NH 8
#define DH 64
#define TQK (3 * DM)   // 1536
#define QSCALE 0.18033688011112042f   // log2(e)/8 : folds softmax scale + base-2 exp

typedef __attribute__((ext_vector_type(8))) short bf16x8;
typedef __attribute__((ext_vector_type(4))) float floatx4;
typedef unsigned short ushort_t;

__device__ __forceinline__ floatx4 mfma16(bf16x8 a, bf16x8 b, floatx4 c) {
    return __builtin_amdgcn_mfma_f32_16x16x32_bf16(a, b, c, 0, 0, 0);
}
__device__ __forceinline__ float ex2(float x) { return __builtin_amdgcn_exp2f(x); }

__device__ __forceinline__ unsigned int pk2(float a, float b) {
    unsigned int ua = __float_as_uint(a); ua = (ua + 0x7FFFu + ((ua >> 16) & 1u)) >> 16;
    unsigned int ub = __float_as_uint(b); ub = (ub + 0x7FFFu + ((ub >> 16) & 1u)) >> 16;
    return ua | (ub << 16);
}
__device__ __forceinline__ unsigned short f2bf(float x) {
    unsigned int u = __float_as_uint(x);
    return (unsigned short)((u + 0x7FFFu + ((u >> 16) & 1u)) >> 16);
}
__device__ __forceinline__ float bflo(unsigned int u) { return __uint_as_float(u << 16); }
__device__ __forceinline__ float bfhi(unsigned int u) { return __uint_as_float(u & 0xFFFF0000u); }

__device__ __forceinline__ void gload_lds16(const void* g, void* l) {
    __builtin_amdgcn_global_load_lds(
        (const __attribute__((address_space(1))) unsigned int*)g,
        (__attribute__((address_space(3))) unsigned int*)l, 16, 0, 0);
}

#define DPPMAX(x, ctrl) \
    (x) = fmaxf((x), __int_as_float(__builtin_amdgcn_update_dpp(0, __float_as_int(x), (ctrl), 0xF, 0xF, true)))
__device__ __forceinline__ float row_max16(float x) {
    DPPMAX(x, 0xB1);   // quad_perm xor1
    DPPMAX(x, 0x4E);   // quad_perm xor2
    DPPMAX(x, 0x141);  // row_half_mirror
    DPPMAX(x, 0x140);  // row_mirror
    return x;
}

// ---------------- fused prep: x->bf16, W_in^T (Q cols pre-scaled), W_out^T ----------------
__global__ __launch_bounds__(256) void prep(const float* __restrict__ x,
                                            const float* __restrict__ W_in,
                                            const float* __restrict__ W_out,
                                            ushort_t* __restrict__ xb,
                                            ushort_t* __restrict__ wti,
                                            ushort_t* __restrict__ wto) {
    __shared__ float T[64][65];
    const int bid = blockIdx.x, tid = threadIdx.x;
    if (bid < 1024) {
        const int i = bid * 256 + tid;
        const float4* p = (const float4*)x + (size_t)i * 2;
        float4 f0 = p[0], f1 = p[1];
        ((uint4*)xb)[i] = make_uint4(pk2(f0.x, f0.y), pk2(f0.z, f0.w),
                                     pk2(f1.x, f1.y), pk2(f1.z, f1.w));
        return;
    }
    const float* W; ushort_t* WT; int N, K, n0, k0; bool qscale;
    if (bid < 1216) { int id = bid - 1024; W = W_in;  WT = wti; N = TQK; K = DM;
                      n0 = (id % 24) * 64; k0 = (id / 24) * 64; qscale = true; }
    else            { int id = bid - 1216; W = W_out; WT = wto; N = DM;  K = DM;
                      n0 = (id % 8) * 64;  k0 = (id / 8) * 64;  qscale = false; }
    {
        const int r = tid >> 2, g = tid & 3;
        const float* src = W + (size_t)(k0 + r) * N + n0 + g * 16;
#pragma unroll
        for (int i = 0; i < 4; i++) {
            float4 f = ((const float4*)src)[i];
            T[g * 16 + i * 4 + 0][r] = f.x;
            T[g * 16 + i * 4 + 1][r] = f.y;
            T[g * 16 + i * 4 + 2][r] = f.z;
            T[g * 16 + i * 4 + 3][r] = f.w;
        }
    }
    __syncthreads();
    const int nr = tid >> 2, g2 = tid & 3;
    const float sc = (qscale && (n0 + nr < DM)) ? QSCALE : 1.0f;
    unsigned int pk[8];
#pragma unroll
    for (int j = 0; j < 8; j++)
        pk[j] = pk2(T[nr][g2 * 16 + 2 * j] * sc, T[nr][g2 * 16 + 2 * j + 1] * sc);
    ushort_t* dst = WT + (size_t)(n0 + nr) * K + k0 + g2 * 16;
    ((uint4*)dst)[0] = make_uint4(pk[0], pk[1], pk[2], pk[3]);
    ((uint4*)dst)[1] = make_uint4(pk[4], pk[5], pk[6], pk[7]);
}

// ---------------- GEMM1: qkv = x @ W_in^T + b_in (bf16 out, V diverted transposed) -------
__global__ __launch_bounds__(256) void gemm_in(const ushort_t* __restrict__ A,
                                               const ushort_t* __restrict__ BT,
                                               const float* __restrict__ bias,
                                               ushort_t* __restrict__ Cv,
                                               ushort_t* __restrict__ vt_out) {
    __shared__ __align__(16) ushort_t As[2][128 * 64];
    __shared__ __align__(16) ushort_t Bs[2][128 * 64];
    const int tid  = threadIdx.x;
    const int lane = tid & 63;
    const int w    = tid >> 6;
    const int quad = lane >> 4;
    const int ln   = lane & 15;
    const int row0 = blockIdx.y * 128;
    const int col0 = blockIdx.x * 128;
    const int wm = w >> 1, wn = w & 1;
    const int srow = lane >> 3;
    const int js   = (lane & 7) ^ srow;
    const int K = DM, N = TQK;

    floatx4 acc[4][4];
#pragma unroll
    for (int i = 0; i < 4; i++)
#pragma unroll
        for (int j = 0; j < 4; j++) acc[i][j] = (floatx4){0.f, 0.f, 0.f, 0.f};

#pragma unroll
    for (int i = 0; i < 4; i++) {
        const int c = w * 4 + i;
        gload_lds16(A  + (size_t)(row0 + c * 8 + srow) * K + js * 8, &As[0][c * 512]);
        gload_lds16(BT + (size_t)(col0 + c * 8 + srow) * K + js * 8, &Bs[0][c * 512]);
    }

    for (int kt = 0; kt < 8; kt++) {
        const int cur = kt & 1;
        __syncthreads();
        if (kt < 7) {
            const int k0n = (kt + 1) << 6;
#pragma unroll
            for (int i = 0; i < 4; i++) {
                const int c = w * 4 + i;
                gload_lds16(A  + (size_t)(row0 + c * 8 + srow) * K + k0n + js * 8, &As[cur ^ 1][c * 512]);
                gload_lds16(BT + (size_t)(col0 + c * 8 + srow) * K + k0n + js * 8, &Bs[cur ^ 1][c * 512]);
            }
        }
#pragma unroll
        for (int s = 0; s < 2; s++) {
            bf16x8 af[4], bfr[4];
#pragma unroll
            for (int i = 0; i < 4; i++) {
                const int lm = wm * 64 + i * 16 + ln;
                af[i] = *(const bf16x8*)&As[cur][lm * 64 + ((s * 4 + quad) ^ (ln & 7)) * 8];
                const int lnn = wn * 64 + i * 16 + ln;
                bfr[i] = *(const bf16x8*)&Bs[cur][lnn * 64 + ((s * 4 + quad) ^ (ln & 7)) * 8];
            }
#pragma unroll
            for (int i = 0; i < 4; i++)
#pragma unroll
                for (int j = 0; j < 4; j++)
                    acc[i][j] = mfma16(af[i], bfr[j], acc[i][j]);
        }
    }

    if (col0 >= 2 * DM) {   // V region -> transposed bf16 [d][seq]
#pragma unroll
        for (int j = 0; j < 4; j++) {
            const int n = col0 + wn * 64 + j * 16 + ln;
            const float bv = bias[n];
#pragma unroll
            for (int i = 0; i < 4; i++) {
                const int mb = row0 + wm * 64 + i * 16 + quad * 4;
                uint2 pkd;
                pkd.x = pk2(acc[i][j][0] + bv, acc[i][j][1] + bv);
                pkd.y = pk2(acc[i][j][2] + bv, acc[i][j][3] + bv);
                *(uint2*)&vt_out[(size_t)(n - 2 * DM) * SEQ + mb] = pkd;
            }
        }
        return;
    }

#pragma unroll
    for (int j = 0; j < 4; j++) {
        const int n = col0 + wn * 64 + j * 16 + ln;
        const float bv = bias[n] * ((n < DM) ? QSCALE : 1.0f);
#pragma unroll
        for (int i = 0; i < 4; i++) {
            const int mb = row0 + wm * 64 + i * 16 + quad * 4;
#pragma unroll
            for (int r = 0; r < 4; r++)
                Cv[(size_t)(mb + r) * N + n] = f2bf(acc[i][j][r] + bv);
        }
    }
}

// ---------------- split-K MFMA flash attention: 256 thr, 4 waves x 32 q-rows -------------
// Round-7 dataflow exactly, but each wave processes 2 q-groups of 16 rows that
// SHARE the K/V fragment reads (16 ds_read_b128 amortized over 32 q-rows).
__global__ __launch_bounds__(256, 3) void attn_split(const ushort_t* __restrict__ qkv_b,
                                                     const ushort_t* __restrict__ vt,
                                                     ushort_t* __restrict__ po,
                                                     float2* __restrict__ pml) {
    __shared__ __align__(16) ushort_t Ks[2][64 * 64];
    __shared__ __align__(16) ushort_t Vs[2][64 * 64];
    __shared__ __align__(16) ushort_t Ps[128 * 72];

    const int tid  = threadIdx.x;
    const int lane = tid & 63;
    const int w    = tid >> 6;          // 0..3
    const int quad = lane >> 4;
    const int ln   = lane & 15;
    const int h    = blockIdx.y;
    const int lnx7 = ln & 7;

    // slot mapping identical to round 7
    const int e = 143 - (int)blockIdx.x;
    int g = 0;
    while (e >= 2 * (g + 1) * (g + 2)) g++;
    const int off = e - 2 * g * (g + 1);
    const int nc  = g + 1;
    const int qt  = 4 * g + off / nc;
    const int c   = off % nc;
    const int T   = 2 * qt + 2;
    const int jt0 = (c * T) / nc;
    const int jt1 = ((c + 1) * T) / nc;
    const int q0  = qt * 128;

    // Q A-frags (bf16, pre-scaled by log2e/8): 2 q-groups
    bf16x8 a0[2], a1[2];
#pragma unroll
    for (int qg = 0; qg < 2; qg++) {
        const ushort_t* qrow = qkv_b + (size_t)(q0 + w * 32 + qg * 16 + ln) * TQK + h * DH;
        a0[qg] = *(const bf16x8*)(qrow + quad * 8);
        a1[qg] = *(const bf16x8*)(qrow + quad * 8 + 32);
    }

    const short oneb = (short)0x3F80;
    const bf16x8 vone = {oneb, oneb, oneb, oneb, oneb, oneb, oneb, oneb};

    float m_q[2] = {-INFINITY, -INFINITY};
    floatx4 o[2][4], ol[2];
#pragma unroll
    for (int qg = 0; qg < 2; qg++) {
#pragma unroll
        for (int t = 0; t < 4; t++) o[qg][t] = (floatx4){0.f, 0.f, 0.f, 0.f};
        ol[qg] = (floatx4){0.f, 0.f, 0.f, 0.f};
    }

    const int srow = lane >> 3;
    const int js   = (lane & 7) ^ srow;

    {   // prologue: stage jt0 into buffer 0 (wave w loads 2 of the 8 row-groups)
        const int k0 = jt0 * 64;
#pragma unroll
        for (int i = 0; i < 2; i++) {
            const int cg = w * 2 + i;
            gload_lds16(qkv_b + (size_t)(k0 + cg * 8 + srow) * TQK + DM + h * DH + js * 8,
                        &Ks[0][cg * 512]);
            gload_lds16(vt + (size_t)(h * DH + cg * 8 + srow) * SEQ + k0 + js * 8,
                        &Vs[0][cg * 512]);
        }
    }

    for (int jt = jt0; jt < jt1; ++jt) {
        const int cur = (jt - jt0) & 1;
        const int k0  = jt * 64;
        __syncthreads();
        if (jt + 1 < jt1) {
            const int k0n = (jt + 1) * 64;
#pragma unroll
            for (int i = 0; i < 2; i++) {
                const int cg = w * 2 + i;
                gload_lds16(qkv_b + (size_t)(k0n + cg * 8 + srow) * TQK + DM + h * DH + js * 8,
                            &Ks[cur ^ 1][cg * 512]);
                gload_lds16(vt + (size_t)(h * DH + cg * 8 + srow) * SEQ + k0n + js * 8,
                            &Vs[cur ^ 1][cg * 512]);
            }
        }

        // ---- K B-frags: read ONCE, shared by both q-groups ----
        bf16x8 kb0[4], kb1[4];
#pragma unroll
        for (int t = 0; t < 4; t++) {
            const int n = t * 16 + ln;
            kb0[t] = *(const bf16x8*)&Ks[cur][n * 64 + ((quad) ^ lnx7) * 8];
            kb1[t] = *(const bf16x8*)&Ks[cur][n * 64 + ((4 + quad) ^ lnx7) * 8];
        }

        // ---- per q-group: S = Q K^T, softmax, P -> LDS ----
#pragma unroll
        for (int qg = 0; qg < 2; qg++) {
            floatx4 sa[4];
#pragma unroll
            for (int t = 0; t < 4; t++) {
                floatx4 acc = {0.f, 0.f, 0.f, 0.f};
                acc = mfma16(a0[qg], kb0[t], acc);
                acc = mfma16(a1[qg], kb1[t], acc);
                sa[t] = acc;
            }

            if (k0 + 63 > q0 + w * 32 + qg * 16) {   // tile may violate causality
#pragma unroll
                for (int t = 0; t < 4; t++) {
                    const int cg2 = k0 + t * 16 + ln;
#pragma unroll
                    for (int r = 0; r < 4; r++) {
                        const int rg = q0 + w * 32 + qg * 16 + quad * 4 + r;
                        if (cg2 > rg) sa[t][r] = -INFINITY;
                    }
                }
            }

            // shared max per quad (4 rows), DPP over the 16-lane row
            float mx = sa[0][0];
#pragma unroll
            for (int t = 0; t < 4; t++)
#pragma unroll
                for (int r = 0; r < 4; r++) mx = fmaxf(mx, sa[t][r]);
            mx = row_max16(mx);
            const float mn = fmaxf(fmaxf(m_q[qg], mx), -1e30f);
            const float alpha = ex2(m_q[qg] - mn);
            m_q[qg] = mn;
#pragma unroll
            for (int t = 0; t < 4; t++)
#pragma unroll
                for (int r = 0; r < 4; r++) {
                    const float p = ex2(sa[t][r] - mn);
                    Ps[(w * 32 + qg * 16 + quad * 4 + r) * 72 + t * 16 + ln] =
                        (ushort_t)(__float_as_uint(p) >> 16);
                }
            if (alpha < 1.0f) {
#pragma unroll
                for (int t = 0; t < 4; t++)
#pragma unroll
                    for (int r = 0; r < 4; r++) o[qg][t][r] *= alpha;
#pragma unroll
                for (int r = 0; r < 4; r++) ol[qg][r] *= alpha;
            }
        }

        __builtin_amdgcn_wave_barrier();   // order P writes before A-frag reads (same wave)

        // ---- V B-frags: read ONCE, shared; PV for both q-groups ----
#pragma unroll
        for (int t = 0; t < 4; t++) {
            const int d = t * 16 + ln;
            const bf16x8 v0 = *(const bf16x8*)&Vs[cur][d * 64 + ((quad) ^ lnx7) * 8];
            const bf16x8 v1 = *(const bf16x8*)&Vs[cur][d * 64 + ((4 + quad) ^ lnx7) * 8];
#pragma unroll
            for (int qg = 0; qg < 2; qg++) {
                const bf16x8 p0 = *(const bf16x8*)&Ps[(w * 32 + qg * 16 + ln) * 72 + quad * 8];
                const bf16x8 p1 = *(const bf16x8*)&Ps[(w * 32 + qg * 16 + ln) * 72 + quad * 8 + 32];
                o[qg][t] = mfma16(p0, v0, o[qg][t]);
                o[qg][t] = mfma16(p1, v1, o[qg][t]);
                if (t == 0) {
                    ol[qg] = mfma16(p0, vone, ol[qg]);
                    ol[qg] = mfma16(p1, vone, ol[qg]);
                }
            }
        }
    }

    // partials: unnormalized bf16 O + fp32 (m,l); slot = e
    const size_t pbase  = ((size_t)h * 144 + e) * (128 * 64);
    const size_t mlbase = ((size_t)h * 144 + e) * 128;
#pragma unroll
    for (int qg = 0; qg < 2; qg++) {
#pragma unroll
        for (int t = 0; t < 4; t++)
#pragma unroll
            for (int r = 0; r < 4; r++)
                po[pbase + (size_t)(w * 32 + qg * 16 + quad * 4 + r) * 64 + t * 16 + ln] =
                    f2bf(o[qg][t][r]);
        if (ln == 0) {
#pragma unroll
            for (int r = 0; r < 4; r++)
                pml[mlbase + w * 32 + qg * 16 + quad * 4 + r] = make_float2(m_q[qg], ol[qg][r]);
        }
    }
}

// ---------------- combine partials -> attn_out bf16 [SEQ][DM] ----------------
__global__ __launch_bounds__(512) void attn_combine(const ushort_t* __restrict__ po,
                                                    const float2* __restrict__ pml,
                                                    ushort_t* __restrict__ aob) {
    const int qt = blockIdx.x, h = blockIdx.y;
    const int gq = qt >> 2;
    const int nc = gq + 1;
    const int sbase = 2 * gq * (gq + 1) + (qt & 3) * nc;
    const int row = threadIdx.x >> 2, g = threadIdx.x & 3;

    float2 ml[8];
    float M = -INFINITY;
    for (int ci = 0; ci < nc; ci++) {
        ml[ci] = pml[((size_t)h * 144 + sbase + ci) * 128 + row];
        M = fmaxf(M, ml[ci].x);
    }
    float L = 0.f;
    float acc[16];
#pragma unroll
    for (int j = 0; j < 16; j++) acc[j] = 0.f;

    for (int ci = 0; ci < nc; ci++) {
        const float wgt = ex2(ml[ci].x - M);
        L += wgt * ml[ci].y;
        const ushort_t* p = po + ((size_t)h * 144 + sbase + ci) * (128 * 64)
                               + (size_t)row * 64 + g * 16;
        uint4 u0 = ((const uint4*)p)[0];
        uint4 u1 = ((const uint4*)p)[1];
        const unsigned int uu[8] = {u0.x, u0.y, u0.z, u0.w, u1.x, u1.y, u1.z, u1.w};
#pragma unroll
        for (int j = 0; j < 8; j++) {
            acc[2 * j]     += wgt * bflo(uu[j]);
            acc[2 * j + 1] += wgt * bfhi(uu[j]);
        }
    }
    const float inv = 1.0f / L;
    unsigned int pk[8];
#pragma unroll
    for (int j = 0; j < 8; j++)
        pk[j] = pk2(acc[2 * j] * inv, acc[2 * j + 1] * inv);
    ushort_t* dst = aob + (size_t)(qt * 128 + row) * DM + h * DH + g * 16;
    ((uint4*)dst)[0] = make_uint4(pk[0], pk[1], pk[2], pk[3]);
    ((uint4*)dst)[1] = make_uint4(pk[4], pk[5], pk[6], pk[7]);
}

// ---------------- GEMM2: out = aob @ W_out^T + b_out (fp32), 128x64 tiles ----------------
__global__ __launch_bounds__(256) void gemm_out(const ushort_t* __restrict__ A,
                                                const ushort_t* __restrict__ BT,
                                                const float* __restrict__ bias,
                                                float* __restrict__ out) {
    __shared__ __align__(16) ushort_t As[2][128 * 64];
    __shared__ __align__(16) ushort_t Bs[2][64 * 64];
    const int tid  = threadIdx.x;
    const int lane = tid & 63;
    const int w    = tid >> 6;
    const int quad = lane >> 4;
    const int ln   = lane & 15;
    const int row0 = blockIdx.y * 128;
    const int col0 = blockIdx.x * 64;
    const int wm = w >> 1, wn = w & 1;
    const int srow = lane >> 3;
    const int js   = (lane & 7) ^ srow;

    floatx4 acc[4][2];
#pragma unroll
    for (int i = 0; i < 4; i++)
#pragma unroll
        for (int j = 0; j < 2; j++) acc[i][j] = (floatx4){0.f, 0.f, 0.f, 0.f};

#pragma unroll
    for (int i = 0; i < 4; i++) {
        const int c = w * 4 + i;
        gload_lds16(A + (size_t)(row0 + c * 8 + srow) * DM + js * 8, &As[0][c * 512]);
    }
#pragma unroll
    for (int i = 0; i < 2; i++) {
        const int c = w * 2 + i;
        gload_lds16(BT + (size_t)(col0 + c * 8 + srow) * DM + js * 8, &Bs[0][c * 512]);
    }

    for (int kt = 0; kt < 8; kt++) {
        const int cur = kt & 1;
        __syncthreads();
        if (kt < 7) {
            const int k0n = (kt + 1) << 6;
#pragma unroll
            for (int i = 0; i < 4; i++) {
                const int c = w * 4 + i;
                gload_lds16(A + (size_t)(row0 + c * 8 + srow) * DM + k0n + js * 8, &As[cur ^ 1][c * 512]);
            }
#pragma unroll
            for (int i = 0; i < 2; i++) {
                const int c = w * 2 + i;
                gload_lds16(BT + (size_t)(col0 + c * 8 + srow) * DM + k0n + js * 8, &Bs[cur ^ 1][c * 512]);
            }
        }
#pragma unroll
        for (int s = 0; s < 2; s++) {
            bf16x8 af[4], bfr[2];
#pragma unroll
            for (int i = 0; i < 4; i++) {
                const int lm = wm * 64 + i * 16 + ln;
                af[i] = *(const bf16x8*)&As[cur][lm * 64 + ((s * 4 + quad) ^ (ln & 7)) * 8];
            }
#pragma unroll
            for (int j = 0; j < 2; j++) {
                const int lnn = wn * 32 + j * 16 + ln;
                bfr[j] = *(const bf16x8*)&Bs[cur][lnn * 64 + ((s * 4 + quad) ^ (ln & 7)) * 8];
            }
#pragma unroll
            for (int i = 0; i < 4; i++)
#pragma unroll
                for (int j = 0; j < 2; j++)
                    acc[i][j] = mfma16(af[i], bfr[j], acc[i][j]);
        }
    }

#pragma unroll
    for (int j = 0; j < 2; j++) {
        const int n = col0 + wn * 32 + j * 16 + ln;
        const float bv = bias[n];
#pragma unroll
        for (int i = 0; i < 4; i++) {
            const int mb = row0 + wm * 64 + i * 16 + quad * 4;
#pragma unroll
            for (int r = 0; r < 4; r++)
                out[(size_t)(mb + r) * DM + n] = acc[i][j][r] + bv;
        }
    }
}

extern "C" void kernel_launch(void* const* d_in, const int* in_sizes, int n_in,
                              void* d_out, int out_size, void* d_ws, size_t ws_size,
                              hipStream_t stream) {
    const float* x     = (const float*)d_in[0];
    const float* W_in  = (const float*)d_in[1];
    const float* b_in  = (const float*)d_in[2];
    const float* W_out = (const float*)d_in[3];
    const float* b_out = (const float*)d_in[4];
    float* out = (float*)d_out;

    char* ws = (char*)d_ws;
    ushort_t* xb    = (ushort_t*)ws;                    //  4 MB   x bf16 [4096][512]
    ushort_t* wti   = (ushort_t*)(ws + (4u  << 20));    //  1.5 MB W_in^T bf16 (Q cols x QSCALE)
    ushort_t* wto   = (ushort_t*)(ws + (6u  << 20));    //  0.5 MB W_out^T bf16
    ushort_t* qkv_b = (ushort_t*)(ws + (7u  << 20));    // 12 MB   qkv bf16 (V third unused)
    ushort_t* vtb   = (ushort_t*)(ws + (19u << 20));    //  4 MB   V^T bf16 [512][4096]
    ushort_t* po    = (ushort_t*)(ws + (23u << 20));    // 18.9 MB partial O bf16 [8][144][128*64]
    float2*   pml   = (float2*)  (ws + (42u << 20));    //  1.2 MB partial (m,l) [8][144][128]
    ushort_t* aob   = (ushort_t*)(ws + (44u << 20));    //  4 MB   attn out bf16 [4096][512]

    // 0) fused prep: x->bf16 | W_in^T | W_out^T
    prep<<<1280, 256, 0, stream>>>(x, W_in, W_out, xb, wti, wto);

    // 1) qkv = x @ W_in + b_in; Q pre-scaled; V diverted transposed to vtb
    gemm_in<<<dim3(TQK / 128, SEQ / 128), 256, 0, stream>>>(xb, wti, b_in, qkv_b, vtb);

    // 2) split-K causal flash attention -> partials (4 waves x 32 q-rows)
    attn_split<<<dim3(144, NH), 256, 0, stream>>>(qkv_b, vtb, po, pml);

    // 3) merge partials -> aob
    attn_combine<<<dim3(SEQ / 128, NH), 512, 0, stream>>>(po, pml, aob);

    // 4) out = aob @ W_out + b_out (fp32)
    gemm_out<<<dim3(DM / 64, SEQ / 128), 256, 0, stream>>>(aob, wto, b_out, out);
}